// Round 5
// baseline (399.605 us; speedup 1.0000x reference)
//
#include <hip/hip_runtime.h>

#define BATCH 8
#define ROWS  2048
#define WIDTH 4096
#define COLS  4096
#define KB    1024   // WIDTH / 4 (gating blocks along k)
#define CB    1024   // COLS  / 4 (gating blocks along c)
#define RCH   64     // rows per colsum block

typedef float f32x4 __attribute__((ext_vector_type(4)));

// ---------------------------------------------------------------------------
// Kernel 1 (round-1 strip pattern, plain cached loads): xs[b,k] = sum_r X[b,r,k].
// grid = (4, 8, 32) = 1024 blocks; atomics into zeroed xs.
// ---------------------------------------------------------------------------
__global__ __launch_bounds__(256) void colsum_kernel(const f32x4* __restrict__ X,
                                                     float* __restrict__ xs) {
    const int k4 = blockIdx.x * 256 + threadIdx.x;  // k/4 in [0,1024)
    const int b  = blockIdx.y;
    const int r0 = blockIdx.z * RCH;

    const f32x4* p = X + (size_t)(b * ROWS + r0) * (WIDTH / 4) + k4;
    float ax = 0.f, ay = 0.f, az = 0.f, aw = 0.f;
#pragma unroll 8
    for (int r = 0; r < RCH; ++r) {
        f32x4 v = p[(size_t)r * (WIDTH / 4)];
        ax += v.x; ay += v.y; az += v.z; aw += v.w;
    }
    float* dst = xs + (size_t)b * WIDTH + 4 * k4;
    atomicAdd(dst + 0, ax);
    atomicAdd(dst + 1, ay);
    atomicAdd(dst + 2, az);
    atomicAdd(dst + 3, aw);
}

// ---------------------------------------------------------------------------
// Kernel 2: acc = sum_b G[b,kb,cb] * sum_{j<4} xs[b,4kb+j] * W4[4kb+j, cb].
// All 12 global loads (4x W float4, 8x G float) issued up-front for ILP,
// THEN arithmetic. Block partials -> blocksum; last block (device-scope
// ticket) reduces 4096 partials, writes out[0] = s*s. grid = (4, 1024).
// ---------------------------------------------------------------------------
__global__ __launch_bounds__(256) void gated_reduce_kernel(const float* __restrict__ W,
                                                           const float* __restrict__ G,
                                                           const float* __restrict__ xs,
                                                           float* __restrict__ blocksum,
                                                           unsigned* __restrict__ ticket,
                                                           float* __restrict__ out) {
    const int cb = blockIdx.x * 256 + threadIdx.x;  // [0, 1024)
    const int kb = blockIdx.y;                      // [0, 1024)

    const f32x4* Wv = (const f32x4*)W;

    // ---- issue all global loads first (12 in flight per thread) ----
    f32x4 w[4];
#pragma unroll
    for (int j = 0; j < 4; ++j)
        w[j] = Wv[(size_t)(4 * kb + j) * CB + cb];  // W[4kb+j, 4cb..4cb+3]

    float g[8];
#pragma unroll
    for (int b = 0; b < BATCH; ++b)
        g[b] = G[((size_t)b * KB + kb) * CB + cb];

    // ---- arithmetic ----
    float w4[4];
#pragma unroll
    for (int j = 0; j < 4; ++j)
        w4[j] = (w[j].x + w[j].y) + (w[j].z + w[j].w);

    float acc = 0.f;
#pragma unroll
    for (int b = 0; b < BATCH; ++b) {
        float inner = 0.f;
#pragma unroll
        for (int j = 0; j < 4; ++j)
            inner += xs[b * WIDTH + 4 * kb + j] * w4[j];  // block-uniform, L2-hit
        acc += g[b] * inner;
    }

    __shared__ float red[256];
    red[threadIdx.x] = acc;
    __syncthreads();
    for (int o = 128; o > 0; o >>= 1) {
        if (threadIdx.x < o) red[threadIdx.x] += red[threadIdx.x + o];
        __syncthreads();
    }

    const int nblocks = gridDim.x * gridDim.y;  // 4096
    const int bid     = blockIdx.y * gridDim.x + blockIdx.x;
    __shared__ bool amLast;
    if (threadIdx.x == 0) {
        blocksum[bid] = red[0];
        __threadfence();  // release partial before ticket
        unsigned prev = __hip_atomic_fetch_add(ticket, 1u, __ATOMIC_ACQ_REL,
                                               __HIP_MEMORY_SCOPE_AGENT);
        amLast = (prev == (unsigned)(nblocks - 1));
    }
    __syncthreads();

    if (amLast) {  // block-uniform branch
        __threadfence();  // acquire all partials
        float a = 0.f;
        for (int i = threadIdx.x; i < nblocks; i += 256) a += blocksum[i];
        red[threadIdx.x] = a;
        __syncthreads();
        for (int o = 128; o > 0; o >>= 1) {
            if (threadIdx.x < o) red[threadIdx.x] += red[threadIdx.x + o];
            __syncthreads();
        }
        if (threadIdx.x == 0) {
            float s = red[0];
            out[0] = s * s;
        }
    }
}

extern "C" void kernel_launch(void* const* d_in, const int* in_sizes, int n_in,
                              void* d_out, int out_size, void* d_ws, size_t ws_size,
                              hipStream_t stream) {
    const float* X = (const float*)d_in[0];  // (8, 2048, 4096)
    const float* W = (const float*)d_in[1];  // (4096, 4096)
    const float* G = (const float*)d_in[2];  // (8, 1024, 1024)
    float* out = (float*)d_out;              // scalar

    float*    xs       = (float*)d_ws;                     // 32768 floats (atomics)
    unsigned* ticket   = (unsigned*)(xs + BATCH * WIDTH);  // 1 word
    float*    blocksum = xs + BATCH * WIDTH + 8;           // 4096 floats (overwritten)

    // zero atomic targets (xs) + ticket every call — deterministic
    hipMemsetAsync(d_ws, 0, (size_t)(BATCH * WIDTH + 8) * sizeof(float), stream);

    dim3 g1(WIDTH / 4 / 256, BATCH, ROWS / RCH);
    colsum_kernel<<<g1, 256, 0, stream>>>((const f32x4*)X, xs);

    dim3 g2(CB / 256, KB);
    gated_reduce_kernel<<<g2, 256, 0, stream>>>(W, G, xs, blocksum, ticket, out);
}

// Round 6
// 90.132 us; speedup vs baseline: 4.4335x; 4.4335x over previous
//
#include <hip/hip_runtime.h>

#define BATCH 8
#define ROWS  2048
#define WIDTH 4096
#define COLS  4096
#define KB    1024   // WIDTH / 4 (gating blocks along k)
#define CB    1024   // COLS  / 4 (gating blocks along c)
#define RCH   32     // rows per colsum block (2048 blocks -> 8/CU)

typedef float f32x4 __attribute__((ext_vector_type(4)));

// ---------------------------------------------------------------------------
// Kernel 1: xs[b,k] = sum_r X[b,r,k]. Strip pattern (proven fastest), plain
// cached loads, atomics into zeroed xs. grid = (4, 8, 64) = 2048 blocks.
// ---------------------------------------------------------------------------
__global__ __launch_bounds__(256) void colsum_kernel(const f32x4* __restrict__ X,
                                                     float* __restrict__ xs) {
    const int k4 = blockIdx.x * 256 + threadIdx.x;  // k/4 in [0,1024)
    const int b  = blockIdx.y;
    const int r0 = blockIdx.z * RCH;

    const f32x4* p = X + (size_t)(b * ROWS + r0) * (WIDTH / 4) + k4;
    float ax = 0.f, ay = 0.f, az = 0.f, aw = 0.f;
#pragma unroll 8
    for (int r = 0; r < RCH; ++r) {
        f32x4 v = p[(size_t)r * (WIDTH / 4)];
        ax += v.x; ay += v.y; az += v.z; aw += v.w;
    }
    float* dst = xs + (size_t)b * WIDTH + 4 * k4;
    atomicAdd(dst + 0, ax);
    atomicAdd(dst + 1, ay);
    atomicAdd(dst + 2, az);
    atomicAdd(dst + 3, aw);
}

// ---------------------------------------------------------------------------
// Kernel 2: one block per kb. Thread t owns cb = 4t..4t+3:
//   16x float4 W loads (rows 4kb+j, 64B/thread/row) + 8x float4 G loads.
//   acc = sum_b sum_m G[b,kb,4t+m] * sum_j xs[b,4kb+j] * W4[j][m]
// Wave butterfly + LDS -> blocksum[kb]. NO device-scope fences (R4/R5 lesson).
// ---------------------------------------------------------------------------
__global__ __launch_bounds__(256) void gated_kernel(const f32x4* __restrict__ Wv,
                                                    const f32x4* __restrict__ Gv,
                                                    const float* __restrict__ xs,
                                                    float* __restrict__ blocksum) {
    const int t  = threadIdx.x;   // [0,256): cb = 4t..4t+3
    const int kb = blockIdx.x;    // [0,1024)

    f32x4 w[4][4];  // [j][m]: W[4kb+j, 4*(4t+m) .. +3]
#pragma unroll
    for (int j = 0; j < 4; ++j)
#pragma unroll
        for (int m = 0; m < 4; ++m)
            w[j][m] = Wv[(size_t)(4 * kb + j) * CB + 4 * t + m];

    f32x4 g[8];     // G[b, kb, 4t..4t+3]
#pragma unroll
    for (int b = 0; b < 8; ++b)
        g[b] = Gv[((size_t)b * KB + kb) * (CB / 4) + t];

    float w4[4][4];  // column-block sums of W
#pragma unroll
    for (int j = 0; j < 4; ++j)
#pragma unroll
        for (int m = 0; m < 4; ++m)
            w4[j][m] = (w[j][m].x + w[j][m].y) + (w[j][m].z + w[j][m].w);

    float acc = 0.f;
#pragma unroll
    for (int b = 0; b < 8; ++b) {
        float xv[4];
#pragma unroll
        for (int j = 0; j < 4; ++j)
            xv[j] = xs[b * WIDTH + 4 * kb + j];  // block-uniform (SGPR loads)
        float in0 = 0.f, in1 = 0.f, in2 = 0.f, in3 = 0.f;
#pragma unroll
        for (int j = 0; j < 4; ++j) {
            in0 += xv[j] * w4[j][0];
            in1 += xv[j] * w4[j][1];
            in2 += xv[j] * w4[j][2];
            in3 += xv[j] * w4[j][3];
        }
        acc += g[b].x * in0 + g[b].y * in1 + g[b].z * in2 + g[b].w * in3;
    }

    // reduce 256 threads: wave butterfly, then 4 wave-partials via LDS
#pragma unroll
    for (int o = 1; o < 64; o <<= 1) acc += __shfl_xor(acc, o, 64);
    __shared__ float lds[4];
    const int lane = t & 63, wid = t >> 6;
    if (lane == 0) lds[wid] = acc;
    __syncthreads();
    if (t == 0) blocksum[kb] = (lds[0] + lds[1]) + (lds[2] + lds[3]);
}

// ---------------------------------------------------------------------------
// Kernel 3: s = sum(blocksum[0..1024)); out[0] = s*s. One 256-thread block.
// ---------------------------------------------------------------------------
__global__ __launch_bounds__(256) void final_kernel(const f32x4* __restrict__ bs4,
                                                    float* __restrict__ out) {
    f32x4 v = bs4[threadIdx.x];  // 256 float4 = 1024 floats
    float acc = (v.x + v.y) + (v.z + v.w);
    __shared__ float red[256];
    red[threadIdx.x] = acc;
    __syncthreads();
    for (int o = 128; o > 0; o >>= 1) {
        if (threadIdx.x < o) red[threadIdx.x] += red[threadIdx.x + o];
        __syncthreads();
    }
    if (threadIdx.x == 0) {
        float s = red[0];
        out[0] = s * s;
    }
}

extern "C" void kernel_launch(void* const* d_in, const int* in_sizes, int n_in,
                              void* d_out, int out_size, void* d_ws, size_t ws_size,
                              hipStream_t stream) {
    const float* X = (const float*)d_in[0];  // (8, 2048, 4096)
    const float* W = (const float*)d_in[1];  // (4096, 4096)
    const float* G = (const float*)d_in[2];  // (8, 1024, 1024)
    float* out = (float*)d_out;              // scalar

    float* xs       = (float*)d_ws;          // 32768 floats (atomic targets)
    float* blocksum = xs + BATCH * WIDTH;    // 1024 floats (fully overwritten)

    // zero only the atomic accumulator region — deterministic
    hipMemsetAsync(xs, 0, (size_t)BATCH * WIDTH * sizeof(float), stream);

    dim3 g1(WIDTH / 4 / 256, BATCH, ROWS / RCH);
    colsum_kernel<<<g1, 256, 0, stream>>>((const f32x4*)X, xs);

    gated_kernel<<<KB, 256, 0, stream>>>((const f32x4*)W, (const f32x4*)G, xs, blocksum);

    final_kernel<<<1, 256, 0, stream>>>((const f32x4*)blocksum, out);
}

// Round 7
// 81.826 us; speedup vs baseline: 4.8836x; 1.1015x over previous
//
#include <hip/hip_runtime.h>

#define BATCH 8
#define ROWS  2048
#define WIDTH 4096
#define COLS  4096
#define KB    1024   // WIDTH/4 gating blocks along k
#define CBV   1024   // COLS/4  float4s per W row
#define ZPART 32     // row-chunks per batch (partials)
#define RCH   64     // ROWS / ZPART

typedef float f32x4 __attribute__((ext_vector_type(4)));

// ---------------------------------------------------------------------------
// Kernel 1: part[z][b][k] = sum_{r in chunk z} X[b,r,k].
// NO atomics, NO memset needed — every element overwritten each call.
// grid = (4, 8, 32) = 1024 blocks; coalesced f32x4 stores (4 MB total).
// ---------------------------------------------------------------------------
__global__ __launch_bounds__(256) void colsum_kernel(const f32x4* __restrict__ X,
                                                     f32x4* __restrict__ part) {
    const int k4 = blockIdx.x * 256 + threadIdx.x;  // [0, 1024)
    const int b  = blockIdx.y;
    const int z  = blockIdx.z;

    const f32x4* p = X + (size_t)(b * ROWS + z * RCH) * (WIDTH / 4) + k4;
    f32x4 a = {0.f, 0.f, 0.f, 0.f};
#pragma unroll 8
    for (int r = 0; r < RCH; ++r) {
        f32x4 v = p[(size_t)r * (WIDTH / 4)];
        a.x += v.x; a.y += v.y; a.z += v.z; a.w += v.w;
    }
    part[((size_t)(z * BATCH + b) << 10) + k4] = a;
}

// ---------------------------------------------------------------------------
// Kernel 2: one block per kb.
//  Phase A: reduce xs[b, 4kb..4kb+3] = sum_z part[z][b][kb] — one f32x4 load
//           per thread (z=t>>3, b=t&7), 3 wave butterflies (z strides), LDS.
//  Phase B: thread t owns cb = 4t..4t+3:
//           acc = sum_b sum_m G[b,kb,4t+m] * sum_j xs[b,4kb+j]*W4[4kb+j,4t+m]
//  Wave butterfly + LDS -> blocksum[kb]. No atomics, no fences.
// ---------------------------------------------------------------------------
__global__ __launch_bounds__(256) void gated_kernel(const f32x4* __restrict__ Wv,
                                                    const f32x4* __restrict__ Gv,
                                                    const f32x4* __restrict__ part,
                                                    float* __restrict__ blocksum) {
    const int t  = threadIdx.x;   // [0,256)
    const int kb = blockIdx.x;    // [0,1024)
    const int lane = t & 63, wv = t >> 6;

    // ---- phase A: xs partial for (z = t>>3, b = t&7) ----
    f32x4 v = part[((size_t)((t >> 3) * BATCH + (t & 7)) << 10) + kb];

    // ---- issue independent W/G loads early ----
    f32x4 w[4][4];  // [j][m]: W[4kb+j, 16t+4m .. +3]
#pragma unroll
    for (int j = 0; j < 4; ++j)
#pragma unroll
        for (int m = 0; m < 4; ++m)
            w[j][m] = Wv[(size_t)(4 * kb + j) * CBV + 4 * t + m];

    f32x4 g[8];     // G[b, kb, 4t..4t+3]
#pragma unroll
    for (int b = 0; b < 8; ++b)
        g[b] = Gv[((size_t)(b * KB + kb) << 8) + t];

    // ---- finish phase A: butterfly over z (lane strides 8,16,32) ----
#pragma unroll
    for (int o = 8; o < 64; o <<= 1) {
        v.x += __shfl_xor(v.x, o, 64);
        v.y += __shfl_xor(v.y, o, 64);
        v.z += __shfl_xor(v.z, o, 64);
        v.w += __shfl_xor(v.w, o, 64);
    }
    __shared__ f32x4 ldsx[4][8];
    if (lane < 8) ldsx[wv][lane] = v;  // lane == b here
    __syncthreads();
    f32x4 xs4[8];
#pragma unroll
    for (int b = 0; b < 8; ++b)
        xs4[b] = (ldsx[0][b] + ldsx[1][b]) + (ldsx[2][b] + ldsx[3][b]);

    // ---- phase B ----
    float w4[4][4];  // 4-col block sums of W
#pragma unroll
    for (int j = 0; j < 4; ++j)
#pragma unroll
        for (int m = 0; m < 4; ++m)
            w4[j][m] = (w[j][m].x + w[j][m].y) + (w[j][m].z + w[j][m].w);

    float acc = 0.f;
#pragma unroll
    for (int b = 0; b < 8; ++b) {
        float in0 = 0.f, in1 = 0.f, in2 = 0.f, in3 = 0.f;
#pragma unroll
        for (int j = 0; j < 4; ++j) {
            const float xv = (j == 0) ? xs4[b].x : (j == 1) ? xs4[b].y
                                                 : (j == 2) ? xs4[b].z : xs4[b].w;
            in0 += xv * w4[j][0];
            in1 += xv * w4[j][1];
            in2 += xv * w4[j][2];
            in3 += xv * w4[j][3];
        }
        acc += g[b].x * in0 + g[b].y * in1 + g[b].z * in2 + g[b].w * in3;
    }

    // ---- block reduce -> blocksum[kb] ----
#pragma unroll
    for (int o = 1; o < 64; o <<= 1) acc += __shfl_xor(acc, o, 64);
    __shared__ float ldss[4];
    if (lane == 0) ldss[wv] = acc;
    __syncthreads();
    if (t == 0) blocksum[kb] = (ldss[0] + ldss[1]) + (ldss[2] + ldss[3]);
}

// ---------------------------------------------------------------------------
// Kernel 3: s = sum(blocksum[0..1024)); out[0] = s*s. One 256-thread block.
// ---------------------------------------------------------------------------
__global__ __launch_bounds__(256) void final_kernel(const f32x4* __restrict__ bs4,
                                                    float* __restrict__ out) {
    f32x4 v = bs4[threadIdx.x];  // 256 float4 = 1024 floats
    float acc = (v.x + v.y) + (v.z + v.w);
    __shared__ float red[256];
    red[threadIdx.x] = acc;
    __syncthreads();
    for (int o = 128; o > 0; o >>= 1) {
        if (threadIdx.x < o) red[threadIdx.x] += red[threadIdx.x + o];
        __syncthreads();
    }
    if (threadIdx.x == 0) {
        float s = red[0];
        out[0] = s * s;
    }
}

extern "C" void kernel_launch(void* const* d_in, const int* in_sizes, int n_in,
                              void* d_out, int out_size, void* d_ws, size_t ws_size,
                              hipStream_t stream) {
    const float* X = (const float*)d_in[0];  // (8, 2048, 4096)
    const float* W = (const float*)d_in[1];  // (4096, 4096)
    const float* G = (const float*)d_in[2];  // (8, 1024, 1024)
    float* out = (float*)d_out;              // scalar

    float* part     = (float*)d_ws;                       // 32*8*4096 f32 = 4 MB
    float* blocksum = part + (size_t)ZPART * BATCH * WIDTH;  // 1024 f32

    dim3 g1(WIDTH / 4 / 256, BATCH, ZPART);
    colsum_kernel<<<g1, 256, 0, stream>>>((const f32x4*)X, (f32x4*)part);

    gated_kernel<<<KB, 256, 0, stream>>>((const f32x4*)W, (const f32x4*)G,
                                         (const f32x4*)part, blocksum);

    final_kernel<<<1, 256, 0, stream>>>((const f32x4*)blocksum, out);
}

// Round 8
// 79.695 us; speedup vs baseline: 5.0142x; 1.0267x over previous
//
#include <hip/hip_runtime.h>

#define BATCH 8
#define ROWS  2048
#define WIDTH 4096
#define COLS  4096
#define KB    1024   // WIDTH/4 gating blocks along k
#define CBV   1024   // COLS/4  float4s per W row
#define ZPART 32     // row-chunks per batch (partials)
#define RCH   64     // ROWS / ZPART

typedef float f32x4 __attribute__((ext_vector_type(4)));

// ---------------------------------------------------------------------------
// Fused kernel, 2048 blocks, parity-interleaved so both streams co-reside:
//   even bid (1024): colsum — part[z][b][k] = sum_{r in chunk z} X[b,r,k]
//   odd  bid (1024): gate   — wg[b, 4kb+j] = sum_c W[4kb+j, c] * G[b, kb, c/4]
// (gate is independent of X — no ordering needed). No atomics, no fences.
// ---------------------------------------------------------------------------
__global__ __launch_bounds__(256) void fused_kernel(const f32x4* __restrict__ X,
                                                    const f32x4* __restrict__ Wv,
                                                    const f32x4* __restrict__ Gv,
                                                    f32x4* __restrict__ part,
                                                    float* __restrict__ wg) {
    const int t = threadIdx.x;
    if (!(blockIdx.x & 1)) {
        // ---------------- colsum: strip pattern (proven) --------------------
        const int s  = blockIdx.x >> 1;     // [0, 1024)
        const int k4 = (s & 3) * 256 + t;   // [0, 1024)
        const int b  = (s >> 2) & 7;
        const int z  = s >> 5;              // [0, 32)

        const f32x4* p = X + (size_t)(b * ROWS + z * RCH) * (WIDTH / 4) + k4;
        f32x4 a = {0.f, 0.f, 0.f, 0.f};
#pragma unroll 8
        for (int r = 0; r < RCH; ++r) {
            f32x4 v = p[(size_t)r * (WIDTH / 4)];
            a.x += v.x; a.y += v.y; a.z += v.z; a.w += v.w;
        }
        part[((size_t)(z * BATCH + b) << 10) + k4] = a;
    } else {
        // ---------------- gate: one block per kb ----------------------------
        const int kb = blockIdx.x >> 1;     // [0, 1024)
        const int lane = t & 63, wv = t >> 6;

        f32x4 w[4][4];  // [j][m]: W[4kb+j, 4*(4t+m) .. +3]
#pragma unroll
        for (int j = 0; j < 4; ++j)
#pragma unroll
            for (int m = 0; m < 4; ++m)
                w[j][m] = Wv[(size_t)(4 * kb + j) * CBV + 4 * t + m];

        f32x4 g[8];     // G[b, kb, 4t..4t+3]
#pragma unroll
        for (int b = 0; b < 8; ++b)
            g[b] = Gv[((size_t)(b * KB + kb) << 8) + t];

        float w4[4][4];  // 4-col block sums of W
#pragma unroll
        for (int j = 0; j < 4; ++j)
#pragma unroll
            for (int m = 0; m < 4; ++m)
                w4[j][m] = (w[j][m].x + w[j][m].y) + (w[j][m].z + w[j][m].w);

        float acc[8][4];
#pragma unroll
        for (int b = 0; b < 8; ++b)
#pragma unroll
            for (int j = 0; j < 4; ++j)
                acc[b][j] = g[b].x * w4[j][0] + g[b].y * w4[j][1] +
                            g[b].z * w4[j][2] + g[b].w * w4[j][3];

        // reduce 32 accumulators (b,j) across 256 threads
        __shared__ float lds[4][32];
#pragma unroll
        for (int v = 0; v < 32; ++v) {
            float x = acc[v >> 2][v & 3];
#pragma unroll
            for (int o = 1; o < 64; o <<= 1) x += __shfl_xor(x, o, 64);
            if (lane == 0) lds[wv][v] = x;
        }
        __syncthreads();
        if (t < 32) {
            float r = (lds[0][t] + lds[1][t]) + (lds[2][t] + lds[3][t]);
            wg[(size_t)(t >> 2) * WIDTH + 4 * kb + (t & 3)] = r;
        }
    }
}

// ---------------------------------------------------------------------------
// F1: partial[z] = dot(part[z], wg).  32 blocks; wg (128 KB) is L2-hot.
//     sum_z partial[z] = sum_{b,k} xs[b,k] * wg[b,k].
// ---------------------------------------------------------------------------
__global__ __launch_bounds__(256) void dot_kernel(const f32x4* __restrict__ part,
                                                  const f32x4* __restrict__ wgv,
                                                  float* __restrict__ partial) {
    const int z = blockIdx.x;  // [0, 32)
    const f32x4* pz = part + ((size_t)z * BATCH << 10);
    float acc = 0.f;
#pragma unroll
    for (int rep = 0; rep < BATCH * 1024 / 256; ++rep) {  // 32 iters
        const int i = rep * 256 + threadIdx.x;            // (b,k4) flat — same order both arrays
        f32x4 a = pz[i], b = wgv[i];
        acc += a.x * b.x + a.y * b.y + a.z * b.z + a.w * b.w;
    }
#pragma unroll
    for (int o = 1; o < 64; o <<= 1) acc += __shfl_xor(acc, o, 64);
    __shared__ float lds[4];
    const int lane = threadIdx.x & 63, wv = threadIdx.x >> 6;
    if (lane == 0) lds[wv] = acc;
    __syncthreads();
    if (threadIdx.x == 0) partial[z] = (lds[0] + lds[1]) + (lds[2] + lds[3]);
}

// ---------------------------------------------------------------------------
// F2: s = sum(partial[0..32)); out[0] = s*s. One wave.
// ---------------------------------------------------------------------------
__global__ __launch_bounds__(64) void square_kernel(const float* __restrict__ partial,
                                                    float* __restrict__ out) {
    float v = (threadIdx.x < ZPART) ? partial[threadIdx.x] : 0.f;
#pragma unroll
    for (int o = 1; o < 64; o <<= 1) v += __shfl_xor(v, o, 64);
    if (threadIdx.x == 0) out[0] = v * v;
}

extern "C" void kernel_launch(void* const* d_in, const int* in_sizes, int n_in,
                              void* d_out, int out_size, void* d_ws, size_t ws_size,
                              hipStream_t stream) {
    const float* X = (const float*)d_in[0];  // (8, 2048, 4096)
    const float* W = (const float*)d_in[1];  // (4096, 4096)
    const float* G = (const float*)d_in[2];  // (8, 1024, 1024)
    float* out = (float*)d_out;              // scalar

    float* part    = (float*)d_ws;                           // 4 MB, fully rewritten
    float* wg      = part + (size_t)ZPART * BATCH * WIDTH;   // 128 KB, fully rewritten
    float* partial = wg + (size_t)BATCH * WIDTH;             // 32 f32, fully rewritten

    fused_kernel<<<2048, 256, 0, stream>>>((const f32x4*)X, (const f32x4*)W,
                                           (const f32x4*)G, (f32x4*)part, wg);

    dot_kernel<<<ZPART, 256, 0, stream>>>((const f32x4*)part, (const f32x4*)wg, partial);

    square_kernel<<<1, 64, 0, stream>>>(partial, out);
}

// Round 9
// 77.455 us; speedup vs baseline: 5.1592x; 1.0289x over previous
//
#include <hip/hip_runtime.h>

#define BATCH 8
#define ROWS  2048
#define WIDTH 4096
#define COLS  4096
#define KB    1024   // WIDTH/4 gating blocks along k
#define CBV   1024   // COLS/4  float4s per W row
#define ZPART 32     // row-chunks per batch (partials)
#define RCH   64     // ROWS / ZPART
#define NDOT  256    // dot-kernel blocks (z x k-chunk)

typedef float f32x4 __attribute__((ext_vector_type(4)));

// ---------------------------------------------------------------------------
// Fused kernel, 2048 blocks, parity-interleaved so both streams co-reside:
//   even bid (1024): colsum — part[z][b][k] = sum_{r in chunk z} X[b,r,k]
//   odd  bid (1024): gate   — wg[b, 4kb+j] = sum_c W[4kb+j, c] * G[b, kb, c/4]
// (gate is independent of X — no ordering needed). No atomics, no fences.
// ---------------------------------------------------------------------------
__global__ __launch_bounds__(256) void fused_kernel(const f32x4* __restrict__ X,
                                                    const f32x4* __restrict__ Wv,
                                                    const f32x4* __restrict__ Gv,
                                                    f32x4* __restrict__ part,
                                                    float* __restrict__ wg) {
    const int t = threadIdx.x;
    if (!(blockIdx.x & 1)) {
        // ---------------- colsum: strip pattern (proven) --------------------
        const int s  = blockIdx.x >> 1;     // [0, 1024)
        const int k4 = (s & 3) * 256 + t;   // [0, 1024)
        const int b  = (s >> 2) & 7;
        const int z  = s >> 5;              // [0, 32)

        const f32x4* p = X + (size_t)(b * ROWS + z * RCH) * (WIDTH / 4) + k4;
        f32x4 a = {0.f, 0.f, 0.f, 0.f};
#pragma unroll 8
        for (int r = 0; r < RCH; ++r) {
            f32x4 v = p[(size_t)r * (WIDTH / 4)];
            a.x += v.x; a.y += v.y; a.z += v.z; a.w += v.w;
        }
        part[((size_t)(z * BATCH + b) << 10) + k4] = a;
    } else {
        // ---------------- gate: one block per kb ----------------------------
        const int kb = blockIdx.x >> 1;     // [0, 1024)
        const int lane = t & 63, wv = t >> 6;

        f32x4 w[4][4];  // [j][m]: W[4kb+j, 4*(4t+m) .. +3]
#pragma unroll
        for (int j = 0; j < 4; ++j)
#pragma unroll
            for (int m = 0; m < 4; ++m)
                w[j][m] = Wv[(size_t)(4 * kb + j) * CBV + 4 * t + m];

        f32x4 g[8];     // G[b, kb, 4t..4t+3]
#pragma unroll
        for (int b = 0; b < 8; ++b)
            g[b] = Gv[((size_t)(b * KB + kb) << 8) + t];

        float w4[4][4];  // 4-col block sums of W
#pragma unroll
        for (int j = 0; j < 4; ++j)
#pragma unroll
            for (int m = 0; m < 4; ++m)
                w4[j][m] = (w[j][m].x + w[j][m].y) + (w[j][m].z + w[j][m].w);

        float acc[8][4];
#pragma unroll
        for (int b = 0; b < 8; ++b)
#pragma unroll
            for (int j = 0; j < 4; ++j)
                acc[b][j] = g[b].x * w4[j][0] + g[b].y * w4[j][1] +
                            g[b].z * w4[j][2] + g[b].w * w4[j][3];

        // reduce 32 accumulators (b,j) across 256 threads
        __shared__ float lds[4][32];
#pragma unroll
        for (int v = 0; v < 32; ++v) {
            float x = acc[v >> 2][v & 3];
#pragma unroll
            for (int o = 1; o < 64; o <<= 1) x += __shfl_xor(x, o, 64);
            if (lane == 0) lds[wv][v] = x;
        }
        __syncthreads();
        if (t < 32) {
            float r = (lds[0][t] + lds[1][t]) + (lds[2][t] + lds[3][t]);
            wg[(size_t)(t >> 2) * WIDTH + 4 * kb + (t & 3)] = r;
        }
    }
}

// ---------------------------------------------------------------------------
// F1: 256 blocks — block (z = bid>>3, kc = bid&7) dots a 16 KB slice of
// part[z] against the matching wg slice (wg chunks go L2-hot).
//   partial[bid] = dot(part[z][slice kc], wg[slice kc])
// ---------------------------------------------------------------------------
__global__ __launch_bounds__(256) void dot_kernel(const f32x4* __restrict__ part,
                                                  const f32x4* __restrict__ wgv,
                                                  float* __restrict__ partial) {
    const int z  = blockIdx.x >> 3;  // [0, 32)
    const int kc = blockIdx.x & 7;   // [0, 8): chunk of 1024 f32x4 in (b,k4) flat space
    const f32x4* pz = part + ((size_t)z * BATCH << 10);

    float acc = 0.f;
#pragma unroll
    for (int rep = 0; rep < 4; ++rep) {
        const int i = (kc << 10) + rep * 256 + threadIdx.x;
        f32x4 a = pz[i], b = wgv[i];
        acc += a.x * b.x + a.y * b.y + a.z * b.z + a.w * b.w;
    }
#pragma unroll
    for (int o = 1; o < 64; o <<= 1) acc += __shfl_xor(acc, o, 64);
    __shared__ float lds[4];
    const int lane = threadIdx.x & 63, wv = threadIdx.x >> 6;
    if (lane == 0) lds[wv] = acc;
    __syncthreads();
    if (threadIdx.x == 0) partial[blockIdx.x] = (lds[0] + lds[1]) + (lds[2] + lds[3]);
}

// ---------------------------------------------------------------------------
// F2: s = sum(partial[0..256)); out[0] = s*s. One 256-thread block.
// ---------------------------------------------------------------------------
__global__ __launch_bounds__(256) void square_kernel(const float* __restrict__ partial,
                                                     float* __restrict__ out) {
    float v = partial[threadIdx.x];
#pragma unroll
    for (int o = 1; o < 64; o <<= 1) v += __shfl_xor(v, o, 64);
    __shared__ float lds[4];
    const int lane = threadIdx.x & 63, wv = threadIdx.x >> 6;
    if (lane == 0) lds[wv] = v;
    __syncthreads();
    if (threadIdx.x == 0) {
        float s = (lds[0] + lds[1]) + (lds[2] + lds[3]);
        out[0] = s * s;
    }
}

extern "C" void kernel_launch(void* const* d_in, const int* in_sizes, int n_in,
                              void* d_out, int out_size, void* d_ws, size_t ws_size,
                              hipStream_t stream) {
    const float* X = (const float*)d_in[0];  // (8, 2048, 4096)
    const float* W = (const float*)d_in[1];  // (4096, 4096)
    const float* G = (const float*)d_in[2];  // (8, 1024, 1024)
    float* out = (float*)d_out;              // scalar

    float* part    = (float*)d_ws;                           // 4 MB, fully rewritten
    float* wg      = part + (size_t)ZPART * BATCH * WIDTH;   // 128 KB, fully rewritten
    float* partial = wg + (size_t)BATCH * WIDTH;             // 256 f32, fully rewritten

    fused_kernel<<<2048, 256, 0, stream>>>((const f32x4*)X, (const f32x4*)W,
                                           (const f32x4*)G, (f32x4*)part, wg);

    dot_kernel<<<NDOT, 256, 0, stream>>>((const f32x4*)part, (const f32x4*)wg, partial);

    square_kernel<<<1, 256, 0, stream>>>(partial, out);
}